// Round 1
// baseline (696.350 us; speedup 1.0000x reference)
//
#include <hip/hip_runtime.h>

#define N_NODES 50000
#define FDIM    128
#define E_EDGES 800000

// ---------------------------------------------------------------------------
// Kernel 1: scatter-add  agg[dst] += w * x[src]
// One wave (64 lanes) per edge; each lane handles 2 features (float2 gather,
// 2 scalar f32 atomics). Block 256 = 4 edges.
// ---------------------------------------------------------------------------
__global__ __launch_bounds__(256) void scatter_kernel(
    const float* __restrict__ x,
    const int*   __restrict__ edge_index,   // [2, E]: row 0 = dst, row 1 = src
    const float* __restrict__ edge_weight,
    float*       __restrict__ agg)
{
    int e = blockIdx.x * 4 + (threadIdx.x >> 6);
    if (e >= E_EDGES) return;
    int lane = threadIdx.x & 63;

    int dst = edge_index[e];
    int src = edge_index[E_EDGES + e];
    float w = edge_weight[e];

    const float2* xrow = reinterpret_cast<const float2*>(x + (size_t)src * FDIM);
    float2 v = xrow[lane];

    float* arow = agg + (size_t)dst * FDIM + lane * 2;
    atomicAdd(arow,     w * v.x);
    atomicAdd(arow + 1, w * v.y);
}

// ---------------------------------------------------------------------------
// Kernel 2: fused epilogue  out = 0.95*x + 0.05*(agg @ W)
// Block 256 threads handles 32 rows. W (128x128 f32, 64 KB) + 32 agg rows
// (16 KB) staged in LDS. Each thread: 4 rows x 4 features register tile.
// ---------------------------------------------------------------------------
__global__ __launch_bounds__(256) void gemm_blend_kernel(
    const float* __restrict__ x,
    const float* __restrict__ agg,
    const float* __restrict__ W,
    float*       __restrict__ out)
{
    __shared__ float sW[FDIM * FDIM];   // 64 KB
    __shared__ float sA[32 * FDIM];     // 16 KB

    const int tid  = threadIdx.x;
    const int row0 = blockIdx.x * 32;

    // Stage W: 16384 floats = 4096 float4 across 256 threads
    {
        const float4* W4  = reinterpret_cast<const float4*>(W);
        float4*       sW4 = reinterpret_cast<float4*>(sW);
        #pragma unroll
        for (int i = 0; i < 16; ++i)
            sW4[tid + i * 256] = W4[tid + i * 256];
    }
    // Stage 32 agg rows: 4096 floats = 1024 float4 (guard tail block)
    {
        const int avail_f4 = (N_NODES > row0) ? ((N_NODES - row0) * FDIM) / 4 : 0;
        const float4* A4  = reinterpret_cast<const float4*>(agg + (size_t)row0 * FDIM);
        float4*       sA4 = reinterpret_cast<float4*>(sA);
        #pragma unroll
        for (int i = 0; i < 4; ++i) {
            int idx = tid + i * 256;
            float4 v = make_float4(0.f, 0.f, 0.f, 0.f);
            if (idx < avail_f4) v = A4[idx];
            sA4[idx] = v;
        }
    }
    __syncthreads();

    const int fg = tid & 31;   // feature group: 4 consecutive features
    const int rg = tid >> 5;   // row group: 4 consecutive rows

    float acc[4][4];
    #pragma unroll
    for (int j = 0; j < 4; ++j)
        #pragma unroll
        for (int c = 0; c < 4; ++c) acc[j][c] = 0.f;

    for (int k = 0; k < FDIM; ++k) {
        const float4 wv = *reinterpret_cast<const float4*>(&sW[k * FDIM + fg * 4]);
        #pragma unroll
        for (int j = 0; j < 4; ++j) {
            const float a = sA[(rg * 4 + j) * FDIM + k];
            acc[j][0] += a * wv.x;
            acc[j][1] += a * wv.y;
            acc[j][2] += a * wv.z;
            acc[j][3] += a * wv.w;
        }
    }

    #pragma unroll
    for (int j = 0; j < 4; ++j) {
        const int row = row0 + rg * 4 + j;
        if (row < N_NODES) {
            const float4 xv = *reinterpret_cast<const float4*>(
                &x[(size_t)row * FDIM + fg * 4]);
            float4 o;
            o.x = 0.95f * xv.x + 0.05f * acc[j][0];
            o.y = 0.95f * xv.y + 0.05f * acc[j][1];
            o.z = 0.95f * xv.z + 0.05f * acc[j][2];
            o.w = 0.95f * xv.w + 0.05f * acc[j][3];
            *reinterpret_cast<float4*>(&out[(size_t)row * FDIM + fg * 4]) = o;
        }
    }
}

extern "C" void kernel_launch(void* const* d_in, const int* in_sizes, int n_in,
                              void* d_out, int out_size, void* d_ws, size_t ws_size,
                              hipStream_t stream) {
    const float* x  = (const float*)d_in[0];
    const int*   ei = (const int*)d_in[1];
    const float* ew = (const float*)d_in[2];
    const float* W  = (const float*)d_in[3];
    float* out = (float*)d_out;
    float* agg = (float*)d_ws;   // N_NODES * FDIM floats = 25.6 MB

    const size_t agg_bytes = (size_t)N_NODES * FDIM * sizeof(float);

    // agg must be zeroed every call (harness does not re-poison between replays)
    hipMemsetAsync(agg, 0, agg_bytes, stream);

    // scatter: 4 edges per 256-thread block
    scatter_kernel<<<E_EDGES / 4, 256, 0, stream>>>(x, ei, ew, agg);

    // fused GEMM + residual blend: 32 rows per block
    const int nblk = (N_NODES + 31) / 32;   // 1563
    gemm_blend_kernel<<<nblk, 256, 0, stream>>>(x, agg, W, out);
}